// Round 7
// baseline (206.743 us; speedup 1.0000x reference)
//
#include <hip/hip_runtime.h>
#include <hip/hip_fp16.h>

typedef _Float16 half8 __attribute__((ext_vector_type(8)));
typedef _Float16 half4v __attribute__((ext_vector_type(4)));
typedef float f32x4 __attribute__((ext_vector_type(4)));

#define NSEQ 2048
#define DMOD 1024
#define NHEAD 16
#define DK 64

// async global->LDS, 16B per lane; LDS dest = wave-uniform base + lane*16
#define GLOAD_LDS16(gp, lp) __builtin_amdgcn_global_load_lds(                 \
    (const __attribute__((address_space(1))) void*)(gp),                      \
    (__attribute__((address_space(3))) void*)(lp), 16, 0, 0)

// s_waitcnt imm (gfx9): vmcnt[3:0]=bits[3:0], expcnt=bits[6:4], lgkm=bits[11:8]
#define WAIT_VM(n) (0xF70 | (n))

// ---------------------------------------------------------------------------
// PACKED tile layout for GEMM operands (K=1024):
//   PACK[((st*32 + kc)*64 + ln)*8 + j] = M[st*16 + (ln&15)][kc*32 + (ln>>4)*8 + j]
// One global_load_lds per wave = contiguous 1 KiB burst in fragment order.
// ---------------------------------------------------------------------------

// cast fp32 -> fp16 AND pack into tile order: x (2M) | Wq|Wk|Wv|Wo (1M each)
__global__ __launch_bounds__(256) void cast_pack(
    const float* __restrict__ x, const float* __restrict__ wq,
    const float* __restrict__ wk, const float* __restrict__ wv,
    const float* __restrict__ wo, _Float16* __restrict__ dst)
{
    const int w = blockIdx.x * 4 + (threadIdx.x >> 6);
    const int ln = threadIdx.x & 63, m = ln & 15, qd = ln >> 4;
    const float* src; _Float16* d; int loc;
    if (w < 4096) { src = x; d = dst; loc = w; }                // x: 128 st x 32 kc
    else {
        const int w2 = w - 4096, mat = w2 >> 11;                 // W: 64 st x 32 kc
        loc = w2 & 2047;
        src = mat == 0 ? wq : mat == 1 ? wk : mat == 2 ? wv : wo;
        d = dst + 2097152 + mat * 1048576;
    }
    const int st = loc >> 5, kc = loc & 31;
    const float* p = src + (size_t)(st * 16 + m) * 1024 + kc * 32 + qd * 8;
    float4 a = *(const float4*)p, b = *(const float4*)(p + 4);
    half8 h;
    h[0] = (_Float16)a.x; h[1] = (_Float16)a.y; h[2] = (_Float16)a.z; h[3] = (_Float16)a.w;
    h[4] = (_Float16)b.x; h[5] = (_Float16)b.y; h[6] = (_Float16)b.z; h[7] = (_Float16)b.w;
    *(half8*)(d + (size_t)(loc * 64 + ln) * 8) = h;
}

// bias fp32 -> fp16 (after QKV GEMM; dst overlays dead xh/wqh/wkh)
__global__ __launch_bounds__(256) void cvt_bias(
    const float* __restrict__ src, _Float16* __restrict__ dst)
{
    int i = (blockIdx.x * 256 + threadIdx.x) * 4;
    float4 v = *(const float4*)(src + i);
    half4v h;
    h[0] = (_Float16)v.x; h[1] = (_Float16)v.y;
    h[2] = (_Float16)v.z; h[3] = (_Float16)v.w;
    *(half4v*)(dst + i) = h;
}

// ---------------------------------------------------------------------------
// Tiled GEMM, triple-buffered 2-deep pipelined K-loop (vmcnt(N) + s_barrier),
// PACKED operands (1 KiB burst DMA), lane-ordered fragments.
// C = A @ W^T + bias, K = 1024.  Wave grid 2x2.
// MODE 0: fused QKV epilogue (Q pre-scaled 0.125 at [h][n][dk]; K,V in attn
//         frag-tile order).  MODE 1: fp32 out (final projection).
// ---------------------------------------------------------------------------
template<int BM, int BN, int MODE>
__global__ __launch_bounds__(256) void tgemm(
    const _Float16* __restrict__ A,
    const _Float16* __restrict__ W0, const _Float16* __restrict__ W1,
    const _Float16* __restrict__ W2,
    const float* __restrict__ b0, const float* __restrict__ b1,
    const float* __restrict__ b2,
    _Float16* __restrict__ oQ, _Float16* __restrict__ oK,
    _Float16* __restrict__ oV, float* __restrict__ oF)
{
    constexpr int MT = BM / 32, NT = BN / 32;
    constexpr int NA = BM / 64, NB = BN / 64;   // DMA instrs per wave per step
    __shared__ _Float16 sA[3 * BM * 32];
    __shared__ _Float16 sB[3 * BN * 32];
    const int tid = threadIdx.x, wv = tid >> 6, ln = tid & 63;
    const int m = ln & 15, qd = ln >> 4;
    const int row0 = blockIdx.x * BM;

    int sel = 0, colbase;
    const _Float16* W; const float* bias;
    if constexpr (MODE == 0) {
        sel = blockIdx.y >> 3;
        colbase = (blockIdx.y & 7) * BN;
        W = sel == 0 ? W0 : sel == 1 ? W1 : W2;
        bias = sel == 0 ? b0 : sel == 1 ? b1 : b2;
    } else {
        colbase = blockIdx.y * BN;
        W = W0; bias = b0;
    }
    const int wr = wv >> 1, wc = wv & 1;

    f32x4 acc[MT][NT];
#pragma unroll
    for (int i = 0; i < MT; ++i)
#pragma unroll
        for (int j = 0; j < NT; ++j) acc[i][j] = (f32x4){0.f, 0.f, 0.f, 0.f};

    auto stage = [&](int kc, int b) {
        _Float16* dA = sA + b * (BM * 32);
        _Float16* dB = sB + b * (BN * 32);
#pragma unroll
        for (int ra = 0; ra < NA; ++ra) {
            const int st = ra * 4 + wv;
            GLOAD_LDS16(A + ((size_t)((row0 >> 4) + st) * 32 + kc) * 512 + ln * 8,
                        dA + st * 512);
        }
#pragma unroll
        for (int rb = 0; rb < NB; ++rb) {
            const int st = rb * 4 + wv;
            GLOAD_LDS16(W + ((size_t)((colbase >> 4) + st) * 32 + kc) * 512 + ln * 8,
                        dB + st * 512);
        }
    };
    auto step = [&](int b) {
        const _Float16* cA = sA + b * (BM * 32);
        const _Float16* cB = sB + b * (BN * 32);
        half8 af[MT], bf[NT];
#pragma unroll
        for (int i = 0; i < MT; ++i)
            af[i] = *(const half8*)(cA + ((wr * MT + i) * 64 + ln) * 8);
#pragma unroll
        for (int j = 0; j < NT; ++j)
            bf[j] = *(const half8*)(cB + ((wc * NT + j) * 64 + ln) * 8);
#pragma unroll
        for (int i = 0; i < MT; ++i)
#pragma unroll
            for (int j = 0; j < NT; ++j)
                acc[i][j] = __builtin_amdgcn_mfma_f32_16x16x32_f16(af[i], bf[j], acc[i][j], 0, 0, 0);
    };

    stage(0, 0);
    stage(1, 1);
#pragma unroll
    for (int kc = 0; kc < 31; ++kc) {
        __builtin_amdgcn_s_waitcnt(WAIT_VM(NA + NB));  // step kc's loads done
        __builtin_amdgcn_s_barrier();
        if (kc < 30) stage(kc + 2, (kc + 2) % 3);
        step(kc % 3);
    }
    __builtin_amdgcn_s_waitcnt(WAIT_VM(0));
    __builtin_amdgcn_s_barrier();
    step(1);  // 31 % 3

#pragma unroll
    for (int j = 0; j < NT; ++j) {
        const int col = colbase + wc * (BN / 2) + j * 16 + m;
        const float bv = bias[col];
#pragma unroll
        for (int i = 0; i < MT; ++i) {
            const int crow0 = row0 + wr * (BM / 2) + i * 16 + qd * 4;
            if constexpr (MODE == 1) {
#pragma unroll
                for (int r = 0; r < 4; ++r)
                    oF[(size_t)(crow0 + r) * DMOD + col] = acc[i][j][r] + bv;
            } else {
                const int h = col >> 6, d = col & 63;
                if (sel == 0) {
#pragma unroll
                    for (int r = 0; r < 4; ++r)
                        oQ[h * (NSEQ * DK) + (crow0 + r) * DK + d] =
                            (_Float16)((acc[i][j][r] + bv) * 0.125f);
                } else if (sel == 1) {
                    // K frag-tile order (KIDX)
#pragma unroll
                    for (int r = 0; r < 4; ++r) {
                        const int n = crow0 + r;
                        oK[(size_t)(((h * 16 + (n >> 7)) * 16
                                     + ((n >> 4) & 7) * 2 + (d >> 5)) * 64
                                    + (n & 15) + 16 * ((d >> 3) & 3)) * 8
                           + (d & 7)] = (_Float16)(acc[i][j][r] + bv);
                    }
                } else {
                    // V frag-tile order (VIDX); 4 consecutive n contiguous
                    half4v hv;
#pragma unroll
                    for (int r = 0; r < 4; ++r) hv[r] = (_Float16)(acc[i][j][r] + bv);
                    const int n0 = crow0;
                    *(half4v*)(oV + (size_t)(((h * 16 + (n0 >> 7)) * 16
                                              + ((n0 >> 5) & 3) * 4 + ((d >> 4) & 3)) * 64
                                             + (d & 15) + 16 * ((n0 >> 3) & 3)) * 8
                               + (n0 & 7)) = hv;
                }
            }
        }
    }
}

// ---------------------------------------------------------------------------
// Attention v5: block = (head, 128 q-rows), 4 waves; EACH WAVE OWNS 32 q
// (two 16-q subtiles u=0,1).  Every K/V fragment read from LDS feeds TWO
// MFMAs -> LDS-read cycles per FLOP halved vs v4.  16 kv-steps of 128 keys,
// double-buffered frag-tile K/V staging (1 KiB burst DMA), 1-step prefetch,
// one barrier per step.  Per-256-key softmax, deferred normalization.
// Output written directly in GEMM PACK layout for the out-projection.
// LDS = 32(Kdbuf) + 32(Vdbuf) + 32(P) = 96 KiB -> 1 block/CU.
// ---------------------------------------------------------------------------
__global__ __launch_bounds__(256, 1) void attn(
    const _Float16* __restrict__ Q, const _Float16* __restrict__ Kt,
    const _Float16* __restrict__ Vt, const _Float16* __restrict__ bias_h,
    _Float16* __restrict__ Op)
{
    __shared__ _Float16 sK[2][8192];
    __shared__ _Float16 sV[2][8192];
    __shared__ _Float16 sP[16384];  // [wave][u][2048]
    const int tid = threadIdx.x, wv = tid >> 6, ln = tid & 63;
    const int m = ln & 15, qd = ln >> 4;
    const int h = blockIdx.x;
    const int q0w = blockIdx.y * 128 + wv * 32;   // first q-row of this wave
    const _Float16* Qh = Q + h * (NSEQ * DK);
    const _Float16* Kh = Kt + h * (NSEQ * DK);   // tiled: [step][f2][ln][8]
    const _Float16* Vh = Vt + h * (NSEQ * DK);   // tiled: [step][f][ln][8]
    const _Float16* brow0 = bias_h + (size_t)(q0w + m) * NSEQ;
    const _Float16* brow1 = bias_h + (size_t)(q0w + 16 + m) * NSEQ;

    // Q B-fragments (pre-scaled by 1/8), 2 q-subtiles x 2 dk-halves
    half8 qf[2][2];
#pragma unroll
    for (int u = 0; u < 2; ++u) {
        qf[u][0] = *(const half8*)(Qh + (q0w + u * 16 + m) * DK + qd * 8);
        qf[u][1] = *(const half8*)(Qh + (q0w + u * 16 + m) * DK + 32 + qd * 8);
    }

    f32x4 oacc[2][4], oU[2][4];
#pragma unroll
    for (int u = 0; u < 2; ++u)
#pragma unroll
        for (int v = 0; v < 4; ++v) {
            oacc[u][v] = (f32x4){0.f, 0.f, 0.f, 0.f};
            oU[u][v]   = (f32x4){0.f, 0.f, 0.f, 0.f};
        }
    float bsum[2] = {0.f, 0.f};
    half4v bcur[2][8], bnxt[2][8];

    // prologue: stage step 0 (16 K frags + 16 V frags, 4 per wave each)
#pragma unroll
    for (int j = 0; j < 4; ++j) {
        const int f = j * 4 + wv;
        GLOAD_LDS16(Kh + f * 512 + ln * 8, &sK[0][f * 512]);
        GLOAD_LDS16(Vh + f * 512 + ln * 8, &sV[0][f * 512]);
    }
#pragma unroll
    for (int t = 0; t < 8; ++t) {
        bcur[0][t] = *(const half4v*)(brow0 + t * 16 + qd * 4);
        bcur[1][t] = *(const half4v*)(brow1 + t * 16 + qd * 4);
    }
    __syncthreads();

#pragma unroll 2
    for (int step = 0; step < 16; ++step) {
        // ---- prefetch step+1 (DMA + bias) ----
        if (step < 15) {
            const _Float16* kn = Kh + (step + 1) * 8192;
            const _Float16* vn = Vh + (step + 1) * 8192;
            _Float16* dK = sK[(step + 1) & 1];
            _Float16* dV = sV[(step + 1) & 1];
#pragma unroll
            for (int j = 0; j < 4; ++j) {
                const int f = j * 4 + wv;
                GLOAD_LDS16(kn + f * 512 + ln * 8, dK + f * 512);
                GLOAD_LDS16(vn + f * 512 + ln * 8, dV + f * 512);
            }
#pragma unroll
            for (int t = 0; t < 8; ++t) {
                bnxt[0][t] = *(const half4v*)(brow0 + (step + 1) * 128 + t * 16 + qd * 4);
                bnxt[1][t] = *(const half4v*)(brow1 + (step + 1) * 128 + t * 16 + qd * 4);
            }
        }

        const _Float16* cK = sK[step & 1];
        const _Float16* cV = sV[step & 1];

        // ---- S^T phase: K frag read once, used for BOTH q-subtiles ----
#pragma unroll
        for (int t = 0; t < 8; ++t) {
            half8 kf0 = *(const half8*)(cK + ((t * 2 + 0) * 64 + ln) * 8);
            half8 kf1 = *(const half8*)(cK + ((t * 2 + 1) * 64 + ln) * 8);
#pragma unroll
            for (int u = 0; u < 2; ++u) {
                f32x4 s = {0.f, 0.f, 0.f, 0.f};
                s = __builtin_amdgcn_mfma_f32_16x16x32_f16(kf0, qf[u][0], s, 0, 0, 0);
                s = __builtin_amdgcn_mfma_f32_16x16x32_f16(kf1, qf[u][1], s, 0, 0, 0);
                float p0 = __expf(s[0] - (float)bcur[u][t][0]);
                float p1 = __expf(s[1] - (float)bcur[u][t][1]);
                float p2 = __expf(s[2] - (float)bcur[u][t][2]);
                float p3 = __expf(s[3] - (float)bcur[u][t][3]);
                bsum[u] += (p0 + p1) + (p2 + p3);
                half4v ph;
                ph[0] = (_Float16)p0; ph[1] = (_Float16)p1;
                ph[2] = (_Float16)p2; ph[3] = (_Float16)p3;
                // (q=m, key=t*16+qd*4+r) -> A-frag slot (verified transform)
                *(half4v*)(sP + wv * 4096 + u * 2048 + (t >> 1) * 512
                           + (((t & 1) * 2 + (qd >> 1)) * 16 + m) * 8
                           + (qd & 1) * 4) = ph;
            }
        }

        // ---- PV phase: V frag read once, used for BOTH q-subtiles ----
#pragma unroll
        for (int kk = 0; kk < 4; ++kk) {
            half8 pa0 = *(const half8*)(sP + wv * 4096 + kk * 512 + ln * 8);
            half8 pa1 = *(const half8*)(sP + wv * 4096 + 2048 + kk * 512 + ln * 8);
#pragma unroll
            for (int vt = 0; vt < 4; ++vt) {
                half8 vb = *(const half8*)(cV + ((kk * 4 + vt) * 64 + ln) * 8);
                oU[0][vt] = __builtin_amdgcn_mfma_f32_16x16x32_f16(pa0, vb, oU[0][vt], 0, 0, 0);
                oU[1][vt] = __builtin_amdgcn_mfma_f32_16x16x32_f16(pa1, vb, oU[1][vt], 0, 0, 0);
            }
        }

        // ---- end of 256-key softmax block: fold in 1/(8*sum) ----
        if (step & 1) {
#pragma unroll
            for (int u = 0; u < 2; ++u) {
                float s2 = bsum[u];
                s2 += __shfl_xor(s2, 16, 64);
                s2 += __shfl_xor(s2, 32, 64);
                float inv = 1.0f / (8.0f * s2);
                float iv[4];
#pragma unroll
                for (int r = 0; r < 4; ++r) iv[r] = __shfl(inv, qd * 4 + r, 64);
#pragma unroll
                for (int vt = 0; vt < 4; ++vt) {
#pragma unroll
                    for (int r = 0; r < 4; ++r) oacc[u][vt][r] += iv[r] * oU[u][vt][r];
                    oU[u][vt] = (f32x4){0.f, 0.f, 0.f, 0.f};
                }
                bsum[u] = 0.f;
            }
        }

        if (step < 15) {
#pragma unroll
            for (int t = 0; t < 8; ++t) { bcur[0][t] = bnxt[0][t]; bcur[1][t] = bnxt[1][t]; }
        }
        __syncthreads();
    }

    // ---- store O in PACK layout (out-proj A-operand) ----
    // n = q0w + u*16 + qd*4 + r ; d = h*64 + vt*16 + m
    // idx = ((n>>4)*32 + (d>>5))*512 + ((d>>3)&3)*128 + (n&15)*8 + (d&7)
#pragma unroll
    for (int u = 0; u < 2; ++u) {
        const int st = (q0w >> 4) + u;
#pragma unroll
        for (int vt = 0; vt < 4; ++vt) {
            const int d = h * 64 + vt * 16 + m;
            _Float16* base = Op + (size_t)(st * 32 + (d >> 5)) * 512
                             + ((d >> 3) & 3) * 128 + (d & 7);
#pragma unroll
            for (int r = 0; r < 4; ++r)
                base[(qd * 4 + r) * 8] = (_Float16)oacc[u][vt][r];
        }
    }
}

// ---------------------------------------------------------------------------
extern "C" void kernel_launch(void* const* d_in, const int* in_sizes, int n_in,
                              void* d_out, int out_size, void* d_ws, size_t ws_size,
                              hipStream_t stream)
{
    const float* x  = (const float*)d_in[0];
    const float* db = (const float*)d_in[1];
    const float* Wq = (const float*)d_in[2];
    const float* bq = (const float*)d_in[3];
    const float* Wk = (const float*)d_in[4];
    const float* bk = (const float*)d_in[5];
    const float* Wv = (const float*)d_in[6];
    const float* bv = (const float*)d_in[7];
    const float* Wo = (const float*)d_in[8];
    const float* bo = (const float*)d_in[9];
    float* out = (float*)d_out;

    _Float16* ws  = (_Float16*)d_ws;
    _Float16* xh  = ws;               // 2M: packed x (dead after QKV gemm)
    _Float16* wqh = xh  + 2097152;    // 1M each, packed (wq/wk dead after QKV)
    _Float16* wkh = wqh + 1048576;
    _Float16* wvh = wkh + 1048576;
    _Float16* woh = wvh + 1048576;    // packed, used by out-proj
    _Float16* Qb  = woh + 1048576;    // 2M: [h][n][dk], pre-scaled by 0.125
    _Float16* Kb  = Qb  + 2097152;    // 2M: K frag-tiled (KIDX)
    _Float16* Vtb = Kb  + 2097152;    // 2M: V frag-tiled (VIDX)
    _Float16* Obh = Vtb + 2097152;    // 2M: attention out, PACK layout
    _Float16* bh  = ws;               // 4M: fp16 bias overlays xh+wqh+wkh

    cast_pack<<<3072, 256, 0, stream>>>(x, Wq, Wk, Wv, Wo, xh);

    // fused QKV projection: 128x128 tiles (m97 shape) -> 384 blocks
    tgemm<128, 128, 0><<<dim3(16, 24), 256, 0, stream>>>(
        xh, wqh, wkh, wvh, bq, bk, bv, Qb, Kb, Vtb, nullptr);

    // bias -> fp16 (overlays now-dead xh/wqh/wkh region)
    cvt_bias<<<4096, 256, 0, stream>>>(db, bh);

    attn<<<dim3(NHEAD, NSEQ / 128), 256, 0, stream>>>(Qb, Kb, Vtb, bh, Obh);

    // output projection: 64x128 tiles -> 256 blocks, packed A + W, fp32 out
    tgemm<64, 128, 1><<<dim3(32, 8), 256, 0, stream>>>(
        Obh, woh, nullptr, nullptr, bo, nullptr, nullptr,
        nullptr, nullptr, nullptr, out);
}

// Round 8
// 186.343 us; speedup vs baseline: 1.1095x; 1.1095x over previous
//
#include <hip/hip_runtime.h>
#include <hip/hip_fp16.h>

typedef _Float16 half8 __attribute__((ext_vector_type(8)));
typedef _Float16 half4v __attribute__((ext_vector_type(4)));
typedef float f32x4 __attribute__((ext_vector_type(4)));

#define NSEQ 2048
#define DMOD 1024
#define NHEAD 16
#define DK 64

// async global->LDS, 16B per lane; LDS dest = wave-uniform base + lane*16
#define GLOAD_LDS16(gp, lp) __builtin_amdgcn_global_load_lds(                 \
    (const __attribute__((address_space(1))) void*)(gp),                      \
    (__attribute__((address_space(3))) void*)(lp), 16, 0, 0)

// s_waitcnt imm (gfx9): vmcnt[3:0]=bits[3:0], expcnt=bits[6:4], lgkm=bits[11:8]
#define WAIT_VM(n) (0xF70 | (n))

// ---------------------------------------------------------------------------
// PACKED tile layout for GEMM operands (K=1024):
//   PACK[((st*32 + kc)*64 + ln)*8 + j] = M[st*16 + (ln&15)][kc*32 + (ln>>4)*8 + j]
// One global_load_lds per wave = contiguous 1 KiB burst in fragment order.
// ---------------------------------------------------------------------------

// cast fp32 -> fp16 AND pack into tile order: x (2M) | Wq|Wk|Wv|Wo (1M each)
__global__ __launch_bounds__(256) void cast_pack(
    const float* __restrict__ x, const float* __restrict__ wq,
    const float* __restrict__ wk, const float* __restrict__ wv,
    const float* __restrict__ wo, _Float16* __restrict__ dst)
{
    const int w = blockIdx.x * 4 + (threadIdx.x >> 6);
    const int ln = threadIdx.x & 63, m = ln & 15, qd = ln >> 4;
    const float* src; _Float16* d; int loc;
    if (w < 4096) { src = x; d = dst; loc = w; }                // x: 128 st x 32 kc
    else {
        const int w2 = w - 4096, mat = w2 >> 11;                 // W: 64 st x 32 kc
        loc = w2 & 2047;
        src = mat == 0 ? wq : mat == 1 ? wk : mat == 2 ? wv : wo;
        d = dst + 2097152 + mat * 1048576;
    }
    const int st = loc >> 5, kc = loc & 31;
    const float* p = src + (size_t)(st * 16 + m) * 1024 + kc * 32 + qd * 8;
    float4 a = *(const float4*)p, b = *(const float4*)(p + 4);
    half8 h;
    h[0] = (_Float16)a.x; h[1] = (_Float16)a.y; h[2] = (_Float16)a.z; h[3] = (_Float16)a.w;
    h[4] = (_Float16)b.x; h[5] = (_Float16)b.y; h[6] = (_Float16)b.z; h[7] = (_Float16)b.w;
    *(half8*)(d + (size_t)(loc * 64 + ln) * 8) = h;
}

// bias fp32 -> fp16 (after QKV GEMM; dst overlays dead xh/wqh/wkh)
__global__ __launch_bounds__(256) void cvt_bias(
    const float* __restrict__ src, _Float16* __restrict__ dst)
{
    int i = (blockIdx.x * 256 + threadIdx.x) * 4;
    float4 v = *(const float4*)(src + i);
    half4v h;
    h[0] = (_Float16)v.x; h[1] = (_Float16)v.y;
    h[2] = (_Float16)v.z; h[3] = (_Float16)v.w;
    *(half4v*)(dst + i) = h;
}

// add two fp16 PACK partials (fp32 accumulate), in-place into o
__global__ __launch_bounds__(256) void combine(
    const _Float16* __restrict__ a, const _Float16* __restrict__ b,
    _Float16* __restrict__ o)
{
    int i = (blockIdx.x * 256 + threadIdx.x) * 8;
    half8 x = *(const half8*)(a + i);
    half8 y = *(const half8*)(b + i);
    half8 r;
#pragma unroll
    for (int j = 0; j < 8; ++j) r[j] = (_Float16)((float)x[j] + (float)y[j]);
    *(half8*)(o + i) = r;
}

// ---------------------------------------------------------------------------
// Tiled GEMM, triple-buffered 2-deep pipelined K-loop (vmcnt(N) + s_barrier),
// PACKED operands (1 KiB burst DMA), lane-ordered fragments.
// C = A @ W^T + bias, K = 1024.  Wave grid 2x2.  [unchanged from round 7]
// MODE 0: fused QKV epilogue (Q pre-scaled 0.125 at [h][n][dk]; K,V in attn
//         frag-tile order).  MODE 1: fp32 out (final projection).
// ---------------------------------------------------------------------------
template<int BM, int BN, int MODE>
__global__ __launch_bounds__(256) void tgemm(
    const _Float16* __restrict__ A,
    const _Float16* __restrict__ W0, const _Float16* __restrict__ W1,
    const _Float16* __restrict__ W2,
    const float* __restrict__ b0, const float* __restrict__ b1,
    const float* __restrict__ b2,
    _Float16* __restrict__ oQ, _Float16* __restrict__ oK,
    _Float16* __restrict__ oV, float* __restrict__ oF)
{
    constexpr int MT = BM / 32, NT = BN / 32;
    constexpr int NA = BM / 64, NB = BN / 64;   // DMA instrs per wave per step
    __shared__ _Float16 sA[3 * BM * 32];
    __shared__ _Float16 sB[3 * BN * 32];
    const int tid = threadIdx.x, wv = tid >> 6, ln = tid & 63;
    const int m = ln & 15, qd = ln >> 4;
    const int row0 = blockIdx.x * BM;

    int sel = 0, colbase;
    const _Float16* W; const float* bias;
    if constexpr (MODE == 0) {
        sel = blockIdx.y >> 3;
        colbase = (blockIdx.y & 7) * BN;
        W = sel == 0 ? W0 : sel == 1 ? W1 : W2;
        bias = sel == 0 ? b0 : sel == 1 ? b1 : b2;
    } else {
        colbase = blockIdx.y * BN;
        W = W0; bias = b0;
    }
    const int wr = wv >> 1, wc = wv & 1;

    f32x4 acc[MT][NT];
#pragma unroll
    for (int i = 0; i < MT; ++i)
#pragma unroll
        for (int j = 0; j < NT; ++j) acc[i][j] = (f32x4){0.f, 0.f, 0.f, 0.f};

    auto stage = [&](int kc, int b) {
        _Float16* dA = sA + b * (BM * 32);
        _Float16* dB = sB + b * (BN * 32);
#pragma unroll
        for (int ra = 0; ra < NA; ++ra) {
            const int st = ra * 4 + wv;
            GLOAD_LDS16(A + ((size_t)((row0 >> 4) + st) * 32 + kc) * 512 + ln * 8,
                        dA + st * 512);
        }
#pragma unroll
        for (int rb = 0; rb < NB; ++rb) {
            const int st = rb * 4 + wv;
            GLOAD_LDS16(W + ((size_t)((colbase >> 4) + st) * 32 + kc) * 512 + ln * 8,
                        dB + st * 512);
        }
    };
    auto step = [&](int b) {
        const _Float16* cA = sA + b * (BM * 32);
        const _Float16* cB = sB + b * (BN * 32);
        half8 af[MT], bf[NT];
#pragma unroll
        for (int i = 0; i < MT; ++i)
            af[i] = *(const half8*)(cA + ((wr * MT + i) * 64 + ln) * 8);
#pragma unroll
        for (int j = 0; j < NT; ++j)
            bf[j] = *(const half8*)(cB + ((wc * NT + j) * 64 + ln) * 8);
#pragma unroll
        for (int i = 0; i < MT; ++i)
#pragma unroll
            for (int j = 0; j < NT; ++j)
                acc[i][j] = __builtin_amdgcn_mfma_f32_16x16x32_f16(af[i], bf[j], acc[i][j], 0, 0, 0);
    };

    stage(0, 0);
    stage(1, 1);
#pragma unroll
    for (int kc = 0; kc < 31; ++kc) {
        __builtin_amdgcn_s_waitcnt(WAIT_VM(NA + NB));  // step kc's loads done
        __builtin_amdgcn_s_barrier();
        if (kc < 30) stage(kc + 2, (kc + 2) % 3);
        step(kc % 3);
    }
    __builtin_amdgcn_s_waitcnt(WAIT_VM(0));
    __builtin_amdgcn_s_barrier();
    step(1);  // 31 % 3

#pragma unroll
    for (int j = 0; j < NT; ++j) {
        const int col = colbase + wc * (BN / 2) + j * 16 + m;
        const float bv = bias[col];
#pragma unroll
        for (int i = 0; i < MT; ++i) {
            const int crow0 = row0 + wr * (BM / 2) + i * 16 + qd * 4;
            if constexpr (MODE == 1) {
#pragma unroll
                for (int r = 0; r < 4; ++r)
                    oF[(size_t)(crow0 + r) * DMOD + col] = acc[i][j][r] + bv;
            } else {
                const int h = col >> 6, d = col & 63;
                if (sel == 0) {
#pragma unroll
                    for (int r = 0; r < 4; ++r)
                        oQ[h * (NSEQ * DK) + (crow0 + r) * DK + d] =
                            (_Float16)((acc[i][j][r] + bv) * 0.125f);
                } else if (sel == 1) {
                    // K frag-tile order (KIDX)
#pragma unroll
                    for (int r = 0; r < 4; ++r) {
                        const int n = crow0 + r;
                        oK[(size_t)(((h * 16 + (n >> 7)) * 16
                                     + ((n >> 4) & 7) * 2 + (d >> 5)) * 64
                                    + (n & 15) + 16 * ((d >> 3) & 3)) * 8
                           + (d & 7)] = (_Float16)(acc[i][j][r] + bv);
                    }
                } else {
                    // V frag-tile order (VIDX); 4 consecutive n contiguous
                    half4v hv;
#pragma unroll
                    for (int r = 0; r < 4; ++r) hv[r] = (_Float16)(acc[i][j][r] + bv);
                    const int n0 = crow0;
                    *(half4v*)(oV + (size_t)(((h * 16 + (n0 >> 7)) * 16
                                              + ((n0 >> 5) & 3) * 4 + ((d >> 4) & 3)) * 64
                                             + (d & 15) + 16 * ((n0 >> 3) & 3)) * 8
                               + (n0 & 7)) = hv;
                }
            }
        }
    }
}

// ---------------------------------------------------------------------------
// Attention v6: grid (head, 128-q tile, kv-half) = (16,16,2) = 512 blocks.
// 4 waves, each wave 32 q (2 subtiles, K/V frag reuse across both -> LDS
// reads per FLOP halved).  Each block: 8 kv-steps of 128 keys (its half);
// softmax 256-blocks = step pairs, so each half emits a FULLY NORMALIZED
// partial O (softmax blocks independent; partials simply add).
// LDS = 16(K) + 16(V) + 32(P) = 64 KB -> 2 blocks/CU = 8 waves/CU (the r6
// occupancy that measured 2x-of-floor; r7's 1 wave/SIMD was the regression).
// Single-buffer K/V, 2-barrier step (stall covered by the co-resident block).
// Output: PACK-layout partial at Op + z*2M; combine kernel adds halves.
// ---------------------------------------------------------------------------
__global__ __launch_bounds__(256, 2) void attn(
    const _Float16* __restrict__ Q, const _Float16* __restrict__ Kt,
    const _Float16* __restrict__ Vt, const _Float16* __restrict__ bias_h,
    _Float16* __restrict__ Op)
{
    __shared__ _Float16 sK[8192];
    __shared__ _Float16 sV[8192];
    __shared__ _Float16 sP[16384];  // [wave][u][2048]
    const int tid = threadIdx.x, wv = tid >> 6, ln = tid & 63;
    const int m = ln & 15, qd = ln >> 4;
    const int h = blockIdx.x;
    const int q0w = blockIdx.y * 128 + wv * 32;   // first q-row of this wave
    const int kvb = blockIdx.z * 8;               // first 128-key step of half
    const _Float16* Qh = Q + h * (NSEQ * DK);
    const _Float16* Kh = Kt + h * (NSEQ * DK) + kvb * 8192;  // [step][f][ln][8]
    const _Float16* Vh = Vt + h * (NSEQ * DK) + kvb * 8192;
    const _Float16* brow0 = bias_h + (size_t)(q0w + m) * NSEQ + kvb * 128;
    const _Float16* brow1 = bias_h + (size_t)(q0w + 16 + m) * NSEQ + kvb * 128;

    // Q B-fragments (pre-scaled by 1/8), 2 q-subtiles x 2 dk-halves
    half8 qf[2][2];
#pragma unroll
    for (int u = 0; u < 2; ++u) {
        qf[u][0] = *(const half8*)(Qh + (q0w + u * 16 + m) * DK + qd * 8);
        qf[u][1] = *(const half8*)(Qh + (q0w + u * 16 + m) * DK + 32 + qd * 8);
    }

    f32x4 oacc[2][4], oU[2][4];
#pragma unroll
    for (int u = 0; u < 2; ++u)
#pragma unroll
        for (int v = 0; v < 4; ++v) {
            oacc[u][v] = (f32x4){0.f, 0.f, 0.f, 0.f};
            oU[u][v]   = (f32x4){0.f, 0.f, 0.f, 0.f};
        }
    float bsum[2] = {0.f, 0.f};

    for (int ls = 0; ls < 8; ++ls) {
        if (ls) __syncthreads();   // previous step's LDS reads complete
        // --- stage K,V: 16 frags each, 4 per wave ---
#pragma unroll
        for (int j = 0; j < 4; ++j) {
            const int f = j * 4 + wv;
            GLOAD_LDS16(Kh + ls * 8192 + f * 512 + ln * 8, sK + f * 512);
            GLOAD_LDS16(Vh + ls * 8192 + f * 512 + ln * 8, sV + f * 512);
        }
        // --- bias regs (fp16, 8B/lane); drain together with DMA ---
        half4v bcur[2][8];
#pragma unroll
        for (int t = 0; t < 8; ++t) {
            bcur[0][t] = *(const half4v*)(brow0 + ls * 128 + t * 16 + qd * 4);
            bcur[1][t] = *(const half4v*)(brow1 + ls * 128 + t * 16 + qd * 4);
        }
        __syncthreads();           // staging visible

        // --- S^T phase: K frag read once, used for BOTH q-subtiles ---
#pragma unroll
        for (int t = 0; t < 8; ++t) {
            half8 kf0 = *(const half8*)(sK + ((t * 2 + 0) * 64 + ln) * 8);
            half8 kf1 = *(const half8*)(sK + ((t * 2 + 1) * 64 + ln) * 8);
#pragma unroll
            for (int u = 0; u < 2; ++u) {
                f32x4 s = {0.f, 0.f, 0.f, 0.f};
                s = __builtin_amdgcn_mfma_f32_16x16x32_f16(kf0, qf[u][0], s, 0, 0, 0);
                s = __builtin_amdgcn_mfma_f32_16x16x32_f16(kf1, qf[u][1], s, 0, 0, 0);
                float p0 = __expf(s[0] - (float)bcur[u][t][0]);
                float p1 = __expf(s[1] - (float)bcur[u][t][1]);
                float p2 = __expf(s[2] - (float)bcur[u][t][2]);
                float p3 = __expf(s[3] - (float)bcur[u][t][3]);
                bsum[u] += (p0 + p1) + (p2 + p3);
                half4v ph;
                ph[0] = (_Float16)p0; ph[1] = (_Float16)p1;
                ph[2] = (_Float16)p2; ph[3] = (_Float16)p3;
                // (q=m, key=t*16+qd*4+r) -> A-frag slot (verified transform)
                *(half4v*)(sP + wv * 4096 + u * 2048 + (t >> 1) * 512
                           + (((t & 1) * 2 + (qd >> 1)) * 16 + m) * 8
                           + (qd & 1) * 4) = ph;
            }
        }

        // --- PV phase: V frag read once, used for BOTH q-subtiles ---
#pragma unroll
        for (int kk = 0; kk < 4; ++kk) {
            half8 pa0 = *(const half8*)(sP + wv * 4096 + kk * 512 + ln * 8);
            half8 pa1 = *(const half8*)(sP + wv * 4096 + 2048 + kk * 512 + ln * 8);
#pragma unroll
            for (int vt = 0; vt < 4; ++vt) {
                half8 vb = *(const half8*)(sV + ((kk * 4 + vt) * 64 + ln) * 8);
                oU[0][vt] = __builtin_amdgcn_mfma_f32_16x16x32_f16(pa0, vb, oU[0][vt], 0, 0, 0);
                oU[1][vt] = __builtin_amdgcn_mfma_f32_16x16x32_f16(pa1, vb, oU[1][vt], 0, 0, 0);
            }
        }

        // --- end of a 256-key softmax block: fold in 1/(8*sum) ---
        if (ls & 1) {
#pragma unroll
            for (int u = 0; u < 2; ++u) {
                float s2 = bsum[u];
                s2 += __shfl_xor(s2, 16, 64);
                s2 += __shfl_xor(s2, 32, 64);
                float inv = 1.0f / (8.0f * s2);
                float iv[4];
#pragma unroll
                for (int r = 0; r < 4; ++r) iv[r] = __shfl(inv, qd * 4 + r, 64);
#pragma unroll
                for (int vt = 0; vt < 4; ++vt) {
#pragma unroll
                    for (int r = 0; r < 4; ++r) oacc[u][vt][r] += iv[r] * oU[u][vt][r];
                    oU[u][vt] = (f32x4){0.f, 0.f, 0.f, 0.f};
                }
                bsum[u] = 0.f;
            }
        }
    }

    // ---- store partial O in PACK layout (out-proj A-operand) ----
    // n = q0w + u*16 + qd*4 + r ; d = h*64 + vt*16 + m
    _Float16* Opz = Op + (size_t)blockIdx.z * 2097152;
#pragma unroll
    for (int u = 0; u < 2; ++u) {
        const int st = (q0w >> 4) + u;
#pragma unroll
        for (int vt = 0; vt < 4; ++vt) {
            const int d = h * 64 + vt * 16 + m;
            _Float16* base = Opz + (size_t)(st * 32 + (d >> 5)) * 512
                             + ((d >> 3) & 3) * 128 + (d & 7);
#pragma unroll
            for (int r = 0; r < 4; ++r)
                base[(qd * 4 + r) * 8] = (_Float16)oacc[u][vt][r];
        }
    }
}

// ---------------------------------------------------------------------------
extern "C" void kernel_launch(void* const* d_in, const int* in_sizes, int n_in,
                              void* d_out, int out_size, void* d_ws, size_t ws_size,
                              hipStream_t stream)
{
    const float* x  = (const float*)d_in[0];
    const float* db = (const float*)d_in[1];
    const float* Wq = (const float*)d_in[2];
    const float* bq = (const float*)d_in[3];
    const float* Wk = (const float*)d_in[4];
    const float* bk = (const float*)d_in[5];
    const float* Wv = (const float*)d_in[6];
    const float* bv = (const float*)d_in[7];
    const float* Wo = (const float*)d_in[8];
    const float* bo = (const float*)d_in[9];
    float* out = (float*)d_out;

    _Float16* ws  = (_Float16*)d_ws;
    _Float16* xh  = ws;               // 2M: packed x (dead after QKV gemm)
    _Float16* wqh = xh  + 2097152;    // 1M each, packed (wq/wk dead after QKV)
    _Float16* wkh = wqh + 1048576;
    _Float16* wvh = wkh + 1048576;
    _Float16* woh = wvh + 1048576;    // packed, used by out-proj
    _Float16* Qb  = woh + 1048576;    // 2M: [h][n][dk], pre-scaled by 0.125
    _Float16* Kb  = Qb  + 2097152;    // 2M: K frag-tiled (KIDX)
    _Float16* Vtb = Kb  + 2097152;    // 2M: V frag-tiled (VIDX)
    _Float16* Oh0 = Vtb + 2097152;    // 2M: attn partial (kv-half 0), PACK
    _Float16* Oh1 = Oh0 + 2097152;    // 2M: attn partial (kv-half 1), PACK
    _Float16* bh  = ws;               // 4M: fp16 bias overlays xh+wqh+wkh
    // total ws use: 16M halves = 32 MB

    cast_pack<<<3072, 256, 0, stream>>>(x, Wq, Wk, Wv, Wo, xh);

    // fused QKV projection: 128x128 tiles -> 384 blocks (unchanged r7)
    tgemm<128, 128, 0><<<dim3(16, 24), 256, 0, stream>>>(
        xh, wqh, wkh, wvh, bq, bk, bv, Qb, Kb, Vtb, nullptr);

    // bias -> fp16 (overlays now-dead xh/wqh/wkh region)
    cvt_bias<<<4096, 256, 0, stream>>>(db, bh);

    // attention: (head, q-128-tile, kv-half) = 512 blocks, 2/CU
    attn<<<dim3(NHEAD, NSEQ / 128, 2), 256, 0, stream>>>(Qb, Kb, Vtb, bh, Oh0);

    // add the two kv-half partials (in-place into Oh0)
    combine<<<1024, 256, 0, stream>>>(Oh0, Oh1, Oh0);

    // output projection: 64x128 tiles -> 256 blocks, packed A + W, fp32 out
    tgemm<64, 128, 1><<<dim3(32, 8), 256, 0, stream>>>(
        Oh0, woh, nullptr, nullptr, bo, nullptr, nullptr,
        nullptr, nullptr, nullptr, out);
}